// Round 13
// baseline (272.233 us; speedup 1.0000x reference)
//
#include <hip/hip_runtime.h>

// N=524288, D=9, E=2, H=128, M=32, O=2, K=1.
// LAYOUT (confirmed R6): d_in fp32, d_out FP32 (N*2 outputs + 1 loss).
//
// R13: MFMA with SWAPPED operands (A=weights, B=tokens) so GEMM2 is a
// second MFMA instead of R12's 128-shuffle butterfly (~26cyc each, R7) —
// and the live set fits (R12 spilled: 170 live regs @ VGPR=128, WRITE_SIZE
// +240KB scratch). R12 PROVED the numerics: 3-term split packing + frag
// layouts gave absmax 0.001953125 — reused verbatim (xpk, wfragB).
// D1[hidden,token]: lane g's rows 4g+r == A-frag k-slots 8g+i -> relu'd
// h (bf16-trunc) feeds GEMM2 MFMA directly (K=128 = 4 chained, per expert)
// with B2 = bf16 w2' under permutation kappa(p,8g+i) = 32p+4g+i (i<4),
// 32p+16+4g+i-4 (i>=4). y lands per-lane: col=o (2 used), rows=4 tokens.
// h/w2' truncation error ~2e-4 << output bf16 ulp. Gate stays exact fp32.
#define NTOK 524288
#define TPB  256
#define NBLK (NTOK / TPB)   // 2048

typedef __attribute__((ext_vector_type(8))) short short8v;   // 8 bf16
typedef __attribute__((ext_vector_type(4))) float float4v;   // acc

union FragU { uint4 u; short8v s; };

__device__ __forceinline__ float bf2f(unsigned short u) {
    union { unsigned int i; float f; } v;
    v.i = ((unsigned int)u) << 16;
    return v.f;
}
__device__ __forceinline__ float ldq(const void* p, int i, bool f32) {
    if (f32) return ((const float*)p)[i];
    return bf2f(((const unsigned short*)p)[i]);
}
// truncation split: hi = top-16-bits of fp32 (exact bf16), lo = w - hi
__device__ __forceinline__ unsigned short btrunc(float w) {
    return (unsigned short)(__float_as_uint(w) >> 16);
}
__device__ __forceinline__ float hif(float w) {
    return __uint_as_float(__float_as_uint(w) & 0xFFFF0000u);
}
// pack bf16-trunc(lo), bf16-trunc(hi) -> u32 {low16, high16}
__device__ __forceinline__ unsigned int pk_hi(float lo, float hi) {
    return (__float_as_uint(lo) >> 16) | (__float_as_uint(hi) & 0xFFFF0000u);
}

// ---------------------------------------------------------------------------
// Prep: dtype probe, wgf, bppf, w2f (W2@Wout fp32), wpackF (fallback),
// wfragB (GEMM1 weight frags, PROVEN in R12: slot s<=8 w_hi[s], 9-17
// w_hi[s-9], 18-26 w_lo[s-18], 27 b1_hi, 28 b1_lo; entry (l&15)=hidden
// j=t8*16+(l&15), k-slots 8*(l>>4)+i), and b2c (GEMM2 B-frags, bf16 w2'
// under kappa; layout [o][e][p][g][4 u32], 256 u32).
// ---------------------------------------------------------------------------
__global__ void prep_kernel(const void* __restrict__ num_prop,
                            const void* __restrict__ wgate,
                            const void* __restrict__ W1,
                            const void* __restrict__ b1,
                            const void* __restrict__ W2,
                            const void* __restrict__ b2,
                            const void* __restrict__ Wout,
                            const void* __restrict__ bout,
                            unsigned int* __restrict__ cnt1,
                            int* __restrict__ flag,
                            float* __restrict__ bppf,
                            float* __restrict__ wgf,
                            float* __restrict__ w2f,
                            float* __restrict__ wpackF,
                            unsigned int* __restrict__ wfragB,
                            unsigned int* __restrict__ b2c)
{
    __shared__ unsigned int bad;
    __shared__ int sflag;
    const int t = threadIdx.x;
    if (t == 0) { bad = 0u; *cnt1 = 0u; }
    __syncthreads();
    if (t < 72) {
        const unsigned short* u = (const unsigned short*)num_prop;
        int e = (u[t] >> 7) & 0xFF;
        if (e < 64 || e > 191) atomicOr(&bad, 1u);
    }
    __syncthreads();
    if (t == 0) { sflag = (int)bad; *flag = (int)bad; }
    __syncthreads();
    const bool f32 = (sflag != 0);

    if (t < 18) wgf[t] = ldq(wgate, t, f32);

    if (t < 4) {
        int e = t >> 1, o = t & 1;
        float acc = ldq(bout, o, f32);
        for (int m = 0; m < 32; ++m)
            acc += ldq(b2, e * 32 + m, f32) * ldq(Wout, m * 2 + o, f32);
        bppf[t] = acc;
    }

    {   // per (e,j): fold W2@Wout -> w2f; fp32 record -> wpackF (fallback)
        const int e = t >> 7, j = t & 127;
        float p0 = 0.f, p1 = 0.f;
        for (int m = 0; m < 32; ++m) {
            float w = ldq(W2, (e * 128 + j) * 32 + m, f32);
            p0 += w * ldq(Wout, m * 2 + 0, f32);
            p1 += w * ldq(Wout, m * 2 + 1, f32);
        }
        w2f[e * 256 + j * 2 + 0] = p0;
        w2f[e * 256 + j * 2 + 1] = p1;
        float* dst = wpackF + e * 1536 + j * 12;
        #pragma unroll
        for (int d = 0; d < 9; ++d)
            dst[d] = ldq(W1, (e * 9 + d) * 128 + j, f32);
        dst[9]  = ldq(b1, e * 128 + j, f32);
        dst[10] = p0;
        dst[11] = p1;
    }
    __syncthreads();   // b2c below reads w2f

    {   // b2c entry t: idx = (((o*2+e)*4+p)*4+g)*4 + u
        const int u = t & 3, g = (t >> 2) & 3, p = (t >> 4) & 3;
        const int e = (t >> 6) & 1, o = t >> 7;
        const int i0 = 2 * u, i1 = 2 * u + 1;
        const int j0 = (i0 < 4) ? (32 * p + 4 * g + i0)
                                : (32 * p + 16 + 4 * g + (i0 - 4));
        const int j1 = (i1 < 4) ? (32 * p + 4 * g + i1)
                                : (32 * p + 16 + 4 * g + (i1 - 4));
        const unsigned int v0 = btrunc(w2f[e * 256 + j0 * 2 + o]);
        const unsigned int v1 = btrunc(w2f[e * 256 + j1 * 2 + o]);
        b2c[t] = v0 | (v1 << 16);
    }

    // wfragB: 1024 lane-entries, 4 per thread (VERBATIM from R12 — proven)
    for (int q = 0; q < 4; ++q) {
        const int idx = t + q * 256;          // e*512 + t8*64 + l
        const int e  = idx >> 9;
        const int t8 = (idx >> 6) & 7;
        const int l  = idx & 63;
        const int j  = t8 * 16 + (l & 15);
        const int kg = l >> 4;
        const float bb = ldq(b1, e * 128 + j, f32);
        unsigned int u4[4];
        #pragma unroll
        for (int i = 0; i < 4; ++i) {
            unsigned short v[2];
            #pragma unroll
            for (int h = 0; h < 2; ++h) {
                const int s = kg * 8 + 2 * i + h;
                unsigned short r = 0;
                if (s <= 8) {
                    float w = ldq(W1, (e * 9 + s) * 128 + j, f32);
                    r = btrunc(w);
                } else if (s <= 17) {
                    float w = ldq(W1, (e * 9 + (s - 9)) * 128 + j, f32);
                    r = btrunc(w);
                } else if (s <= 26) {
                    float w = ldq(W1, (e * 9 + (s - 18)) * 128 + j, f32);
                    r = btrunc(w - hif(w));
                } else if (s == 27) {
                    r = btrunc(bb);
                } else if (s == 28) {
                    r = btrunc(bb - hif(bb));
                }
                v[h] = r;
            }
            u4[i] = (unsigned int)v[0] | ((unsigned int)v[1] << 16);
        }
        #pragma unroll
        for (int i = 0; i < 4; ++i) wfragB[idx * 4 + i] = u4[i];
    }
}

// ---------------------------------------------------------------------------
// Main: 256 tokens/block, 4 waves x 4 groups of 16 tokens. Stage xs, exact
// fp32 gate -> eflag; build xpk (token B-frags, PROVEN packing from R12);
// stage b2c->LDS. Per wave: preload 16 GEMM1 weight A-frags (64 VGPR).
// Per group: 1 B-frag read; per p (4): 4 GEMM1 MFMA (2 tiles x 2 experts)
// -> relu -> pk_hi pack -> 2 GEMM2 MFMA (chained C). Select by eflag,
// + bpp, scattered ob write; coalesced float2 store at end. No shuffles.
// ---------------------------------------------------------------------------
__global__ __launch_bounds__(TPB)
void moe_main(const void* __restrict__ xg,
              const int* __restrict__ flag,
              const float* __restrict__ wgf,
              const float* __restrict__ bppf,
              const float* __restrict__ wpackF,
              const unsigned int* __restrict__ wfragB,
              const unsigned int* __restrict__ b2c,
              unsigned int* __restrict__ cnt1,
              float2* __restrict__ out)
{
    __shared__ __align__(16) float xs[TPB * 9];            // 9216 B
    __shared__ __align__(16) unsigned int xpk[TPB * 20];   // 20480 B (padded)
    __shared__ __align__(16) unsigned int b2l[256];        // 1024 B
    __shared__ __align__(16) float obf[TPB * 2];           // 2048 B
    __shared__ __align__(4)  unsigned char eflag[TPB];

    const int tid  = threadIdx.x;
    const int lane = tid & 63;
    const int wave = tid >> 6;
    const bool f32 = (*flag) != 0;
    const int tbase = blockIdx.x * TPB;

    b2l[tid & 255] = b2c[tid & 255];   // stage GEMM2 B-frags (256 u32)

    if (f32) {
        const float4* xf4 = (const float4*)xg;
        float4* xsv = (float4*)xs;
        const int g4 = blockIdx.x * (TPB * 9 / 4);
        #pragma unroll
        for (int i = 0; i < 3; ++i) {
            const int idx = i * 256 + tid;
            if (idx < TPB * 9 / 4) xsv[idx] = xf4[g4 + idx];
        }
    } else {
        const unsigned short* xu = (const unsigned short*)xg;
        const int gbase = blockIdx.x * (TPB * 9);
        for (int i = tid; i < TPB * 9; i += TPB)
            xs[i] = bf2f(xu[gbase + i]);
    }
    __syncthreads();

    // --- exact fp32 gate (same fmaf chain as accepted kernel) ---
    float l0 = 0.f, l1 = 0.f;
    #pragma unroll
    for (int d = 0; d < 9; ++d) {
        const float xv = xs[tid * 9 + d];
        l0 = fmaf(xv, wgf[d * 2 + 0], l0);
        l1 = fmaf(xv, wgf[d * 2 + 1], l1);
    }
    const bool e1 = l1 > l0;              // tie -> expert 0 (stable top_k)
    eflag[tid] = e1 ? 1 : 0;
    unsigned long long bal = __ballot(e1);
    if (lane == 0) atomicAdd(cnt1, (unsigned int)__popcll(bal));

    if (!f32) {
        // bf16 fallback: dense-both via fp32 wpackF from global (never runs)
        float xr[9];
        #pragma unroll
        for (int d = 0; d < 9; ++d) xr[d] = xs[tid * 9 + d];
        float a00 = bppf[0], a01 = bppf[1], a10 = bppf[2], a11 = bppf[3];
        for (int j = 0; j < 128; ++j) {
            const float* r0 = wpackF + j * 12;
            const float* r1 = wpackF + 1536 + j * 12;
            float h0 = r0[9], h1 = r1[9];
            #pragma unroll
            for (int d = 0; d < 9; ++d) {
                h0 = fmaf(xr[d], r0[d], h0);
                h1 = fmaf(xr[d], r1[d], h1);
            }
            h0 = fmaxf(h0, 0.f); h1 = fmaxf(h1, 0.f);
            a00 = fmaf(h0, r0[10], a00); a01 = fmaf(h0, r0[11], a01);
            a10 = fmaf(h1, r1[10], a10); a11 = fmaf(h1, r1[11], a11);
        }
        out[tbase + tid] = make_float2(e1 ? a10 : a00, e1 ? a11 : a01);
        return;
    }

    // --- xpk: split-packed token fragment (VERBATIM from R12 — proven) ---
    {
        unsigned short hv[9], lv[9];
        #pragma unroll
        for (int d = 0; d < 9; ++d) {
            const float xv = xs[tid * 9 + d];
            hv[d] = btrunc(xv);
            lv[d] = btrunc(xv - hif(xv));
        }
        const unsigned int ONE = 0x3F80u;   // bf16 1.0
        #define PK(a,b) ((unsigned int)(a) | ((unsigned int)(b) << 16))
        uint4* xp = (uint4*)&xpk[tid * 20];
        xp[0] = make_uint4(PK(hv[0],hv[1]), PK(hv[2],hv[3]),
                           PK(hv[4],hv[5]), PK(hv[6],hv[7]));
        xp[1] = make_uint4(PK(hv[8],lv[0]), PK(lv[1],lv[2]),
                           PK(lv[3],lv[4]), PK(lv[5],lv[6]));
        xp[2] = make_uint4(PK(lv[7],lv[8]), PK(hv[0],hv[1]),
                           PK(hv[2],hv[3]), PK(hv[4],hv[5]));
        xp[3] = make_uint4(PK(hv[6],hv[7]), PK(hv[8],ONE),
                           PK(ONE,0u), 0u);
        #undef PK
    }
    __syncthreads();

    // --- per-wave preload: 16 GEMM1 weight A-frags (64 VGPR) ---
    FragU wf0[8], wf1[8];
    #pragma unroll
    for (int T = 0; T < 8; ++T) {
        wf0[T].u = ((const uint4*)wfragB)[T * 64 + lane];
        wf1[T].u = ((const uint4*)wfragB)[(8 + T) * 64 + lane];
    }
    const int o  = lane & 15;           // D2 col = output idx (2 used)
    const int g  = lane >> 4;           // lane group
    const int o1 = o & 1;
    const float bpe0 = bppf[o1];        // folded bias, expert 0
    const float bpe1 = bppf[2 + o1];    // expert 1
    const float4v zero4 = {0.f, 0.f, 0.f, 0.f};

    // --- 4 groups of 16 tokens per wave ---
    #pragma unroll 1
    for (int r = 0; r < 4; ++r) {
        const int tb16 = wave * 64 + r * 16;
        FragU bt;   // token B-frag: col = token (lane&15), k = 8g+i
        bt.u = *(const uint4*)&xpk[(tb16 + o) * 20 + (g << 2)];
        const unsigned int efw =
            *(const unsigned int*)&eflag[tb16 + (g << 2)];

        float4v acc0 = zero4, acc1 = zero4;
        #pragma unroll
        for (int p = 0; p < 4; ++p) {
            FragU b2a, b2b;
            b2a.u = *(const uint4*)&b2l[(((o1 * 2 + 0) * 4 + p) * 4 + g) * 4];
            b2b.u = *(const uint4*)&b2l[(((o1 * 2 + 1) * 4 + p) * 4 + g) * 4];
            // GEMM1: D[hidden, token] tiles 2p, 2p+1 for both experts
            float4v d0a = __builtin_amdgcn_mfma_f32_16x16x32_bf16(wf0[2*p].s,   bt.s, zero4, 0, 0, 0);
            float4v d0b = __builtin_amdgcn_mfma_f32_16x16x32_bf16(wf0[2*p+1].s, bt.s, zero4, 0, 0, 0);
            float4v d1a = __builtin_amdgcn_mfma_f32_16x16x32_bf16(wf1[2*p].s,   bt.s, zero4, 0, 0, 0);
            float4v d1b = __builtin_amdgcn_mfma_f32_16x16x32_bf16(wf1[2*p+1].s, bt.s, zero4, 0, 0, 0);
            // relu + bf16-trunc pack into GEMM2 A-frags (k = 8g+i)
            FragU a20, a21;
            a20.u.x = pk_hi(fmaxf(d0a[0], 0.f), fmaxf(d0a[1], 0.f));
            a20.u.y = pk_hi(fmaxf(d0a[2], 0.f), fmaxf(d0a[3], 0.f));
            a20.u.z = pk_hi(fmaxf(d0b[0], 0.f), fmaxf(d0b[1], 0.f));
            a20.u.w = pk_hi(fmaxf(d0b[2], 0.f), fmaxf(d0b[3], 0.f));
            a21.u.x = pk_hi(fmaxf(d1a[0], 0.f), fmaxf(d1a[1], 0.f));
            a21.u.y = pk_hi(fmaxf(d1a[2], 0.f), fmaxf(d1a[3], 0.f));
            a21.u.z = pk_hi(fmaxf(d1b[0], 0.f), fmaxf(d1b[1], 0.f));
            a21.u.w = pk_hi(fmaxf(d1b[2], 0.f), fmaxf(d1b[3], 0.f));
            // GEMM2: y[token, o] accumulate (K chained over p)
            acc0 = __builtin_amdgcn_mfma_f32_16x16x32_bf16(a20.s, b2a.s, acc0, 0, 0, 0);
            acc1 = __builtin_amdgcn_mfma_f32_16x16x32_bf16(a21.s, b2b.s, acc1, 0, 0, 0);
        }

        // select by exact gate + folded bias; D2 rows = tokens tb16+4g+rr
        if (o < 2) {
            #pragma unroll
            for (int rr = 0; rr < 4; ++rr) {
                const int tok = tb16 + (g << 2) + rr;
                const bool sb = (efw >> (8 * rr)) & 1;
                const float y = (sb ? acc1[rr] : acc0[rr]) + (sb ? bpe1 : bpe0);
                obf[tok * 2 + o] = y;
            }
        }
    }
    __syncthreads();
    out[tbase + tid] = ((const float2*)obf)[tid];
}

// Loss: counts-based cv^2 (ddof=1), as validated.
__global__ void finalize_kernel(const unsigned int* __restrict__ cnt1,
                                float* __restrict__ loss_out)
{
    double c1 = (double)(*cnt1);
    double c0 = (double)NTOK - c1;
    double diff = c0 - c1;
    double mean = (double)NTOK * 0.5;
    double var  = 0.5 * diff * diff;
    double cv2  = var / (mean * mean + 1e-10);
    *loss_out = (float)(0.02 * cv2);
}

extern "C" void kernel_launch(void* const* d_in, const int* in_sizes, int n_in,
                              void* d_out, int out_size, void* d_ws, size_t ws_size,
                              hipStream_t stream) {
    const void* num_prop = d_in[0]; // [N,9] fp32
    const void* w_gate   = d_in[2]; // [9,2]
    const void* W1       = d_in[3]; // [2,9,128]
    const void* b1       = d_in[4]; // [2,128]
    const void* W2       = d_in[5]; // [2,128,32]
    const void* b2       = d_in[6]; // [2,32]
    const void* Wout     = d_in[7]; // [32,2]
    const void* bout     = d_in[8]; // [2]

    char* ws = (char*)d_ws;
    unsigned int* cnt1   = (unsigned int*)ws;           // @0
    int* flag            = (int*)(ws + 8);              // @8
    float* bppf          = (float*)(ws + 16);           // 4 f
    float* wgf           = (float*)(ws + 64);           // 18 f
    float* w2f           = (float*)(ws + 192);          // 512 f  -> 2240
    float* wpackF        = (float*)(ws + 2304);         // 3072 f -> 14592
    unsigned int* wfragB = (unsigned int*)(ws + 14592); // 4096 u32 -> 30976
    unsigned int* b2c    = (unsigned int*)(ws + 30976); // 256 u32 -> 32000

    float*  outf = (float*)d_out;                       // FP32: N*2 + loss
    float2* out2 = (float2*)d_out;

    hipLaunchKernelGGL(prep_kernel, dim3(1), dim3(256), 0, stream,
                       num_prop, w_gate, W1, b1, W2, b2, Wout, bout,
                       cnt1, flag, bppf, wgf, w2f, wpackF, wfragB, b2c);
    hipLaunchKernelGGL(moe_main, dim3(NBLK), dim3(TPB), 0, stream,
                       num_prop, flag, wgf, bppf, wpackF, wfragB, b2c,
                       cnt1, out2);
    hipLaunchKernelGGL(finalize_kernel, dim3(1), dim3(1), 0, stream,
                       cnt1, outf + (size_t)NTOK * 2);
}